// Round 9
// baseline (285.758 us; speedup 1.0000x reference)
//
#include <hip/hip_runtime.h>
#include <stdint.h>

typedef short short8 __attribute__((ext_vector_type(8)));
typedef short short4v __attribute__((ext_vector_type(4)));
typedef float f32x4 __attribute__((ext_vector_type(4)));

#define LOG2E 1.44269504088896f
#define AS1 __attribute__((address_space(1)))
#define AS3 __attribute__((address_space(3)))

__device__ __forceinline__ float fexp2(float x) {
#if __has_builtin(__builtin_amdgcn_exp2f)
    return __builtin_amdgcn_exp2f(x);   // bare v_exp_f32 (flush-denorm ok: p<2^-126 ~ 0)
#else
    return exp2f(x);
#endif
}
__device__ __forceinline__ unsigned short f2bfbits(float f) {
    unsigned x = __builtin_bit_cast(unsigned, f);
    unsigned r = x + 0x7fffu + ((x >> 16) & 1u);
    return (unsigned short)(r >> 16);
}
__device__ __forceinline__ float bfbits2f(unsigned short b) {
    unsigned u = ((unsigned)b) << 16;
    return __builtin_bit_cast(float, u);
}
__device__ __forceinline__ void unpack8(uint4 u, float4& f0, float4& f1) {
    f0.x = bfbits2f((unsigned short)(u.x & 0xffffu)); f0.y = bfbits2f((unsigned short)(u.x >> 16));
    f0.z = bfbits2f((unsigned short)(u.y & 0xffffu)); f0.w = bfbits2f((unsigned short)(u.y >> 16));
    f1.x = bfbits2f((unsigned short)(u.z & 0xffffu)); f1.y = bfbits2f((unsigned short)(u.z >> 16));
    f1.z = bfbits2f((unsigned short)(u.w & 0xffffu)); f1.w = bfbits2f((unsigned short)(u.w >> 16));
}
__device__ __forceinline__ unsigned pack2(float a, float b) {
    return (unsigned)f2bfbits(a) | ((unsigned)f2bfbits(b) << 16);
}
// truncating pack (matches P truncation semantics)
__device__ __forceinline__ unsigned pack2t(float a, float b) {
    unsigned ba = __builtin_bit_cast(unsigned, a);
    unsigned bb = __builtin_bit_cast(unsigned, b);
    return (ba >> 16) | (bb & 0xffff0000u);
}
// K=16 bf16 MFMA: A[m=lm][k=quad*4+r], B[k=quad*4+r][n=lm], D[m=quad*4+r][n=lm]
__device__ __forceinline__ f32x4 mfma16(short4v a, short4v b, f32x4 c) {
#if __has_builtin(__builtin_amdgcn_mfma_f32_16x16x16bf16_1k)
    return __builtin_amdgcn_mfma_f32_16x16x16bf16_1k(a, b, c, 0, 0, 0);
#else
    asm("v_mfma_f32_16x16x16_bf16 %0, %1, %2, %0" : "+v"(c) : "v"(a), "v"(b));
    return c;
#endif
}
// async 16B/lane global->LDS; lp must be wave-uniform base, lanes scatter +lane*16
__device__ __forceinline__ void glds16(const void* gp, void* lp) {
    __builtin_amdgcn_global_load_lds((const AS1 unsigned*)(uintptr_t)gp,
                                     (AS3 unsigned*)(unsigned)(uintptr_t)lp, 16, 0, 0);
}

// ------- flat fp32 -> bf16 convert (RNE) -------
__global__ __launch_bounds__(256) void xbf_k(const float* __restrict__ x,
                                             unsigned short* __restrict__ y) {
    int i = (blockIdx.x * 256 + threadIdx.x) * 4;
    float4 v = *(const float4*)(x + i);
    uint2 u;
    u.x = pack2(v.x, v.y);
    u.y = pack2(v.z, v.w);
    *(uint2*)(y + i) = u;
}

// ------- transpose + fp32->bf16 convert: src[R][C] fp32 -> dst[C][R] bf16 -------
__global__ __launch_bounds__(256) void t32cvt_k(const float* __restrict__ src,
                                                unsigned short* __restrict__ dst,
                                                int R, int C) {
    __shared__ float tile[32][36];
    int t = threadIdx.x;
    int bx = blockIdx.x, by = blockIdx.y;
    int r = t >> 3, c0 = (t & 7) * 4;
    *(float4*)&tile[r][c0] = *(const float4*)(src + (size_t)(by * 32 + r) * C + bx * 32 + c0);
    __syncthreads();
    uint2 u;
    u.x = pack2(tile[c0 + 0][r], tile[c0 + 1][r]);
    u.y = pack2(tile[c0 + 2][r], tile[c0 + 3][r]);
    *(uint2*)(dst + (size_t)(bx * 32 + r) * R + by * 32 + c0) = u;
}

// ---- GEMM-256²: 8-wave deep-pipelined kernel (T2 swizzle + T3 phases + T4 counted
// vmcnt + T5 setprio). C[M,N] = A[M,K] bf16 * Bt[N,K]^T bf16.
// Per K-tile (BK=64): front-load all 24 fragment ds_reads -> barrier -> stage tile
// T+2 into the buffer just read -> 64 MFMA -> s_waitcnt vmcnt(8) (tile T+1 landed,
// T+2's 8 loads stay IN FLIGHT across the barrier) -> barrier.
// LDS swizzle S(o) = o ^ ((o>>8&1)<<5) ^ ((o>>9&1)<<4) (shorts) applied on BOTH
// sides: pre-swizzled global column for the linear glds landing, XOR'd read col.
template <bool CF32>
__global__ __launch_bounds__(512, 2) void gemm256_k(const unsigned short* __restrict__ A,
                                                    const unsigned short* __restrict__ Bt,
                                                    void* __restrict__ Cv,
                                                    int M, int N, int K) {
    __shared__ unsigned short sA[2][256 * 64];   // 64 KB
    __shared__ unsigned short sB[2][256 * 64];   // 64 KB
    int t = threadIdx.x;
    int wid = t >> 6, lane = t & 63;
    int wr = wid >> 2, wc = wid & 3;            // 2M x 4N wave grid
    int lm = lane & 15, lq = lane >> 4;
    int nwg = gridDim.x * gridDim.y;
    int orig = blockIdx.y * gridDim.x + blockIdx.x;
    int swzb = (orig & 7) * (nwg >> 3) + (orig >> 3);   // XCD swizzle (nwg%8==0)
    int bxi = swzb % gridDim.x, byi = swzb / gridDim.x;
    size_t m0 = (size_t)byi * 256, n0 = (size_t)bxi * 256;
    // staging: thread t covers LDS linear offset q*4096 + t*8 shorts; fetches the
    // global column that belongs at the SWIZZLED location (bit8->+32, bit9->+16)
    int srow = t >> 3;
    int scol = ((t & 7) * 8) ^ (((t >> 5) & 1) << 5) ^ (((t >> 6) & 1) << 4);
    const unsigned short* gA = A + (m0 + srow) * K + scol;
    const unsigned short* gB = Bt + (n0 + srow) * K + scol;
    int lbase = wid * 512;                       // per-wave landing base within 4096-chunk
    int cxor = ((lm & 4) << 3) | ((lm & 8) << 1);  // read-side swizzle (row bits 2,3)

    auto STAGE256 = [&](int T, int b) {
        int k0_ = T * 64;
        #pragma unroll
        for (int q = 0; q < 4; ++q) {
            glds16(gA + (size_t)q * 64 * K + k0_, &sA[b][q * 4096 + lbase]);
            glds16(gB + (size_t)q * 64 * K + k0_, &sB[b][q * 4096 + lbase]);
        }
    };

    f32x4 acc[8][4] = {};
    STAGE256(0, 0);
    STAGE256(1, 1);
    asm volatile("s_waitcnt vmcnt(8)" ::: "memory");   // tile0's 8 landed; tile1 in flight
    __builtin_amdgcn_s_barrier();

    #pragma unroll 1
    for (int T = 0; T < 16; ++T) {
        int cur = T & 1;
        const unsigned short* Ab = sA[cur];
        const unsigned short* Bb = sB[cur];
        short8 af[8][2], bfr[4][2];
        #pragma unroll
        for (int i = 0; i < 8; ++i)
            #pragma unroll
            for (int kk = 0; kk < 2; ++kk)
                af[i][kk] = *(const short8*)&Ab[(wr * 128 + i * 16 + lm) * 64 + ((kk * 32 + lq * 8) ^ cxor)];
        #pragma unroll
        for (int j = 0; j < 4; ++j)
            #pragma unroll
            for (int kk = 0; kk < 2; ++kk)
                bfr[j][kk] = *(const short8*)&Bb[(wc * 64 + j * 16 + lm) * 64 + ((kk * 32 + lq * 8) ^ cxor)];
        __builtin_amdgcn_sched_barrier(0);     // reads pinned before barrier
        __builtin_amdgcn_s_barrier();          // all waves issued reads of buf[cur]
        __builtin_amdgcn_sched_barrier(0);
        if (T + 2 < 16) STAGE256(T + 2, cur);  // overwrite cur (reads retire ~120cy;
                                               // glds writes land >=300cy post-barrier)
        __builtin_amdgcn_sched_barrier(0);
        __builtin_amdgcn_s_setprio(1);
        #pragma unroll
        for (int i = 0; i < 8; ++i)
            #pragma unroll
            for (int j = 0; j < 4; ++j) {
                acc[i][j] = __builtin_amdgcn_mfma_f32_16x16x32_bf16(af[i][0], bfr[j][0], acc[i][j], 0, 0, 0);
                acc[i][j] = __builtin_amdgcn_mfma_f32_16x16x32_bf16(af[i][1], bfr[j][1], acc[i][j], 0, 0, 0);
            }
        __builtin_amdgcn_s_setprio(0);
        __builtin_amdgcn_sched_barrier(0);
        if (T < 14) {
            asm volatile("s_waitcnt vmcnt(8)" ::: "memory");   // tile T+1 done; T+2 in flight
        } else if (T == 14) {
            asm volatile("s_waitcnt vmcnt(0)" ::: "memory");   // tail: tile 15 done
        }
        __builtin_amdgcn_s_barrier();          // tile T+1 visible to all waves
    }
    #pragma unroll
    for (int i = 0; i < 8; ++i)
        #pragma unroll
        for (int j = 0; j < 4; ++j)
            #pragma unroll
            for (int r = 0; r < 4; ++r) {
                size_t row = m0 + wr * 128 + i * 16 + lq * 4 + r;
                size_t col = n0 + wc * 64 + j * 16 + lm;
                if (CF32) ((float*)Cv)[row * N + col] = acc[i][j][r];
                else ((unsigned short*)Cv)[row * N + col] = f2bfbits(acc[i][j][r]);
            }
}

// ---- GEMM (2-phase 128², proven): C[M,N] = A[M,K] bf16 * Bt[N,K]^T ; used for gemm2
template <bool CF32>
__global__ __launch_bounds__(256) void gemm_k(const unsigned short* __restrict__ A,
                                              const unsigned short* __restrict__ Bt,
                                              void* __restrict__ Cv,
                                              int M, int N, int K) {
    __shared__ unsigned short sA[2][128 * 32];   // [row][32] unpadded (glds16 linear)
    __shared__ unsigned short sB[2][128 * 32];
    int t = threadIdx.x;
    int wid = t >> 6, lane = t & 63;
    int wm = (wid >> 1) * 64, wn = (wid & 1) * 64;
    int lm = lane & 15, lq = lane >> 4;
    int nwg = gridDim.x * gridDim.y;
    int orig = blockIdx.y * gridDim.x + blockIdx.x;
    int swz = (orig & 7) * (nwg >> 3) + (orig >> 3);
    int bxi = swz % gridDim.x, byi = swz / gridDim.x;
    size_t m0 = (size_t)byi * 128, n0 = (size_t)bxi * 128;
    int srow = t >> 2, scol = (t & 3) * 8;
    const unsigned short* ga0 = A + (m0 + srow) * K + scol;
    const unsigned short* ga1 = A + (m0 + 64 + srow) * K + scol;
    const unsigned short* gb0 = Bt + (n0 + srow) * K + scol;
    const unsigned short* gb1 = Bt + (n0 + 64 + srow) * K + scol;
    int l0 = wid * 512, l1 = 2048 + wid * 512;

    glds16(ga0, &sA[0][l0]);
    glds16(ga1, &sA[0][l1]);
    glds16(gb0, &sB[0][l0]);
    glds16(gb1, &sB[0][l1]);

    f32x4 acc[4][4] = {};
    int cur = 0;
    for (int k0 = 0; k0 < K; k0 += 32) {
        __syncthreads();
        if (k0 + 32 < K) {
            glds16(ga0 + k0 + 32, &sA[cur ^ 1][l0]);
            glds16(ga1 + k0 + 32, &sA[cur ^ 1][l1]);
            glds16(gb0 + k0 + 32, &sB[cur ^ 1][l0]);
            glds16(gb1 + k0 + 32, &sB[cur ^ 1][l1]);
        }
        short8 af[4], bfr[4];
        #pragma unroll
        for (int i = 0; i < 4; ++i) af[i] = *(const short8*)&sA[cur][(wm + i * 16 + lm) * 32 + lq * 8];
        #pragma unroll
        for (int j = 0; j < 4; ++j) bfr[j] = *(const short8*)&sB[cur][(wn + j * 16 + lm) * 32 + lq * 8];
        __builtin_amdgcn_s_setprio(1);
        #pragma unroll
        for (int i = 0; i < 4; ++i)
            #pragma unroll
            for (int j = 0; j < 4; ++j)
                acc[i][j] = __builtin_amdgcn_mfma_f32_16x16x32_bf16(af[i], bfr[j], acc[i][j], 0, 0, 0);
        __builtin_amdgcn_s_setprio(0);
        cur ^= 1;
    }
    #pragma unroll
    for (int i = 0; i < 4; ++i)
        #pragma unroll
        for (int j = 0; j < 4; ++j)
            #pragma unroll
            for (int r = 0; r < 4; ++r) {
                size_t row = m0 + wm + i * 16 + lq * 4 + r;
                size_t col = n0 + wn + j * 16 + lm;
                if (CF32) ((float*)Cv)[row * N + col] = acc[i][j][r];
                else ((unsigned short*)Cv)[row * N + col] = f2bfbits(acc[i][j][r]);
            }
}

// ------- V transpose: per (b,h): V[2048 k][64 d] -> Vt[64 d][2048 k], bf16 -------
__global__ __launch_bounds__(256) void vt_k(const unsigned short* __restrict__ qkv,
                                            unsigned short* __restrict__ vt) {
    __shared__ unsigned short tile[64 * 72];
    int kt = blockIdx.x, bh = blockIdx.y;
    int b = bh >> 4, h = bh & 15;
    const unsigned short* Vp = qkv + (size_t)b * 6291456 + 4194304 + (size_t)h * 131072;
    int t = threadIdx.x;
    int row = t >> 2, cc = (t & 3) * 16;
    const unsigned short* src = Vp + (size_t)(kt * 64 + row) * 64 + cc;
    *(uint4*)&tile[row * 72 + cc] = *(const uint4*)src;
    *(uint4*)&tile[row * 72 + cc + 8] = *(const uint4*)(src + 8);
    __syncthreads();
    unsigned v[8];
    #pragma unroll
    for (int j = 0; j < 8; ++j) {
        unsigned short a = tile[(cc + 2 * j) * 72 + row];
        unsigned short bsh = tile[(cc + 2 * j + 1) * 72 + row];
        v[j] = (unsigned)a | ((unsigned)bsh << 16);
    }
    unsigned short* dst = vt + ((size_t)bh * 64 + row) * 2048 + kt * 64 + cc;
    *(uint4*)dst = make_uint4(v[0], v[1], v[2], v[3]);
    *(uint4*)(dst + 8) = make_uint4(v[4], v[5], v[6], v[7]);
}

// ------- MFMA flash attention: block = (b,h, 128-q); 4 waves x 32 q -------
// (round-4 best-measured variant, 94.3 us) Reg-resident P (swapped QK^T -> x16 PV).
// Double-buffered K/V LDS in T14 order: prefetch EARLY (after barrier), ds_write
// LATE (after compute) into the other buffer -> 1 barrier/kt, no VGPR WAR window.
__global__ __launch_bounds__(256, 4) void attn_mfma(const unsigned short* __restrict__ qkv,
                                                    const unsigned short* __restrict__ vt,
                                                    unsigned short* __restrict__ aout) {
    __shared__ unsigned short Ks[2][64 * 72];  // [kk 64][d 64] pad 72
    __shared__ unsigned short Vs[2][64 * 72];  // [d 64][kk 64] pad 72
    int bid0 = blockIdx.x;
    int bid = (bid0 & 7) * 128 + (bid0 >> 3);  // XCD swizzle, nwg=1024 (%8==0 -> bijective)
    int qt = bid & 15, h = (bid >> 4) & 15, b = bid >> 8;
    int t = threadIdx.x;
    int wave = t >> 6, lane = t & 63, lm = lane & 15, quad = lane >> 4;
    const unsigned short* Qb = qkv + (size_t)b * 6291456 + (size_t)h * 131072;
    const unsigned short* Kb = Qb + 2097152;
    const unsigned short* Vtb = vt + (size_t)(b * 16 + h) * 131072;  // [64][2048]
    int q0 = qt * 128 + wave * 32;

    // persistent Q fragments, pre-scaled by 0.125 * log2(e) (folds softmax scale + exp2 base)
    const float qs = 0.125f * LOG2E;
    short8 qf[2][2];
    #pragma unroll
    for (int i = 0; i < 2; ++i)
        #pragma unroll
        for (int c = 0; c < 2; ++c) {
            uint4 u = *(const uint4*)(Qb + (size_t)(q0 + i * 16 + lm) * 64 + c * 32 + quad * 8);
            float4 f0, f1; unpack8(u, f0, f1);
            uint4 v;
            v.x = pack2(f0.x * qs, f0.y * qs);
            v.y = pack2(f0.z * qs, f0.w * qs);
            v.z = pack2(f1.x * qs, f1.y * qs);
            v.w = pack2(f1.z * qs, f1.w * qs);
            qf[i][c] = *(short8*)&v;
        }

    short4v ones4;
    #pragma unroll
    for (int z = 0; z < 4; ++z) ones4[z] = (short)0x3F80;  // bf16 1.0

    f32x4 o[2][4] = {};
    f32x4 l_acc[2] = {};

    int srow = t >> 2, scol = (t & 3) * 16;

    // prologue: load tile 0 and stage it into buf0
    uint4 k0r, k1r, v0r, v1r;
    {
        const unsigned short* kp = Kb + (size_t)srow * 64 + scol;
        k0r = *(const uint4*)kp;
        k1r = *(const uint4*)(kp + 8);
        const unsigned short* vp = Vtb + (size_t)srow * 2048 + scol;
        v0r = *(const uint4*)vp;
        v1r = *(const uint4*)(vp + 8);
        *(uint4*)&Ks[0][srow * 72 + scol] = k0r;
        *(uint4*)&Ks[0][srow * 72 + scol + 8] = k1r;
        *(uint4*)&Vs[0][srow * 72 + scol] = v0r;
        *(uint4*)&Vs[0][srow * 72 + scol + 8] = v1r;
    }

    #pragma unroll 1
    for (int kt = 0; kt < 32; ++kt) {
        __syncthreads();   // buf[kt&1] (staged at end of prev iter / prologue) visible

        // issue next tile's global loads now; they land during this tile's compute
        if (kt < 31) {
            const unsigned short* kp = Kb + (size_t)((kt + 1) * 64 + srow) * 64 + scol;
            k0r = *(const uint4*)kp;
            k1r = *(const uint4*)(kp + 8);
            const unsigned short* vp = Vtb + (size_t)srow * 2048 + (kt + 1) * 64 + scol;
            v0r = *(const uint4*)vp;
            v1r = *(const uint4*)(vp + 8);
        }

        const unsigned short* ks = Ks[kt & 1];
        const unsigned short* vs = Vs[kt & 1];
        __builtin_amdgcn_s_setprio(1);

        // S^T = K Q^T per 16x16 tile: mfma(kf, qf) -> D[row=k-local][col=q-local].
        // Lane (lm,quad) holds P[q=i*16+lm][k=j*16+quad*4+0..3] == A-fragment of the
        // K=16 MFMA -> exp2+pack to short4 in registers, feed PV directly.
        short4v pf[2][4];
        #pragma unroll
        for (int j = 0; j < 4; ++j) {
            short8 kf0 = *(const short8*)&ks[(j * 16 + lm) * 72 + quad * 8];
            short8 kf1 = *(const short8*)&ks[(j * 16 + lm) * 72 + 32 + quad * 8];
            #pragma unroll
            for (int i = 0; i < 2; ++i) {
                f32x4 sf = {0.f, 0.f, 0.f, 0.f};
                sf = __builtin_amdgcn_mfma_f32_16x16x32_bf16(kf0, qf[i][0], sf, 0, 0, 0);
                sf = __builtin_amdgcn_mfma_f32_16x16x32_bf16(kf1, qf[i][1], sf, 0, 0, 0);
                uint2 u;
                u.x = pack2t(fexp2(sf[0]), fexp2(sf[1]));
                u.y = pack2t(fexp2(sf[2]), fexp2(sf[3]));
                pf[i][j] = *(short4v*)&u;
            }
        }

        // O += P V (K=16 MFMA, P from regs; V fragment = ds_read_b64 from Vt layout)
        #pragma unroll
        for (int jd = 0; jd < 4; ++jd)
            #pragma unroll
            for (int j = 0; j < 4; ++j) {
                short4v vf = *(const short4v*)&vs[(jd * 16 + lm) * 72 + j * 16 + quad * 4];
                o[0][jd] = mfma16(pf[0][j], vf, o[0][jd]);
                o[1][jd] = mfma16(pf[1][j], vf, o[1][jd]);
            }
        // l += P * ones (row-sums on MFMA pipe, same D layout as o)
        #pragma unroll
        for (int j = 0; j < 4; ++j) {
            l_acc[0] = mfma16(pf[0][j], ones4, l_acc[0]);
            l_acc[1] = mfma16(pf[1][j], ones4, l_acc[1]);
        }
        __builtin_amdgcn_s_setprio(0);

        // write-late: stage tile kt+1 into the other buffer. Safe with 1 barrier/kt:
        // any wave's reads of buf[(kt+1)&1] (its compute at kt-1) completed before it
        // arrived at barrier(kt), which this wave has passed.
        if (kt < 31) {
            unsigned short* kd = Ks[(kt + 1) & 1];
            unsigned short* vd = Vs[(kt + 1) & 1];
            *(uint4*)&kd[srow * 72 + scol] = k0r;
            *(uint4*)&kd[srow * 72 + scol + 8] = k1r;
            *(uint4*)&vd[srow * 72 + scol] = v0r;
            *(uint4*)&vd[srow * 72 + scol + 8] = v1r;
        }
    }
    // epilogue: aout[b*2048 + q][h*64 + d] bf16
    #pragma unroll
    for (int i = 0; i < 2; ++i)
        #pragma unroll
        for (int r = 0; r < 4; ++r) {
            float inv = 1.f / l_acc[i][r];
            int q = q0 + i * 16 + quad * 4 + r;
            size_t rowbase = ((size_t)b * 2048 + q) * 1024 + h * 64;
            #pragma unroll
            for (int jd = 0; jd < 4; ++jd)
                aout[rowbase + jd * 16 + lm] = f2bfbits(o[i][jd][r] * inv);
        }
}

extern "C" void kernel_launch(void* const* d_in, const int* in_sizes, int n_in,
                              void* d_out, int out_size, void* d_ws, size_t ws_size,
                              hipStream_t stream) {
    const float* xin  = (const float*)d_in[0];   // [8192,1024] fp32
    const float* wqkv = (const float*)d_in[1];   // [1024,3072] fp32
    const float* wo   = (const float*)d_in[2];   // [1024,1024] fp32
    float* out = (float*)d_out;                  // [8192,1024] fp32

    char* ws = (char*)d_ws;
    unsigned short* qkv   = (unsigned short*)(ws);                 // 50,331,648 B
    unsigned short* attn  = (unsigned short*)(ws + 50331648);      // 16,777,216 B
    unsigned short* wqkvT = (unsigned short*)(ws + 67108864);      //  6,291,456 B
    unsigned short* woT   = (unsigned short*)(ws + 73400320);      //  2,097,152 B
    unsigned short* vt    = (unsigned short*)(ws + 75497472);      // 16,777,216 B
    unsigned short* xb    = (unsigned short*)(ws + 92274688);      // 16,777,216 B

    dim3 blk(256);
    xbf_k<<<dim3(8192), blk, 0, stream>>>(xin, xb);
    t32cvt_k<<<dim3(3072 / 32, 1024 / 32), blk, 0, stream>>>(wqkv, wqkvT, 1024, 3072);
    t32cvt_k<<<dim3(1024 / 32, 1024 / 32), blk, 0, stream>>>(wo, woT, 1024, 1024);
    gemm256_k<false><<<dim3(3072 / 256, 8192 / 256), dim3(512), 0, stream>>>(xb, wqkvT, qkv, 8192, 3072, 1024);
    vt_k<<<dim3(32, 64), blk, 0, stream>>>(qkv, vt);
    attn_mfma<<<dim3(1024), blk, 0, stream>>>(qkv, vt, attn);
    gemm_k<true><<<dim3(1024 / 128, 8192 / 128), blk, 0, stream>>>(attn, woT, out, 8192, 1024, 1024);
}

// Round 10
// 268.724 us; speedup vs baseline: 1.0634x; 1.0634x over previous
//
#include <hip/hip_runtime.h>
#include <stdint.h>

typedef short short8 __attribute__((ext_vector_type(8)));
typedef short short4v __attribute__((ext_vector_type(4)));
typedef float f32x4 __attribute__((ext_vector_type(4)));

#define LOG2E 1.44269504088896f
#define AS1 __attribute__((address_space(1)))
#define AS3 __attribute__((address_space(3)))

__device__ __forceinline__ float fexp2(float x) {
#if __has_builtin(__builtin_amdgcn_exp2f)
    return __builtin_amdgcn_exp2f(x);   // bare v_exp_f32 (flush-denorm ok: p<2^-126 ~ 0)
#else
    return exp2f(x);
#endif
}
__device__ __forceinline__ unsigned short f2bfbits(float f) {
    unsigned x = __builtin_bit_cast(unsigned, f);
    unsigned r = x + 0x7fffu + ((x >> 16) & 1u);
    return (unsigned short)(r >> 16);
}
__device__ __forceinline__ float bfbits2f(unsigned short b) {
    unsigned u = ((unsigned)b) << 16;
    return __builtin_bit_cast(float, u);
}
__device__ __forceinline__ void unpack8(uint4 u, float4& f0, float4& f1) {
    f0.x = bfbits2f((unsigned short)(u.x & 0xffffu)); f0.y = bfbits2f((unsigned short)(u.x >> 16));
    f0.z = bfbits2f((unsigned short)(u.y & 0xffffu)); f0.w = bfbits2f((unsigned short)(u.y >> 16));
    f1.x = bfbits2f((unsigned short)(u.z & 0xffffu)); f1.y = bfbits2f((unsigned short)(u.z >> 16));
    f1.z = bfbits2f((unsigned short)(u.w & 0xffffu)); f1.w = bfbits2f((unsigned short)(u.w >> 16));
}
__device__ __forceinline__ unsigned pack2(float a, float b) {
    return (unsigned)f2bfbits(a) | ((unsigned)f2bfbits(b) << 16);
}
// truncating pack (matches P truncation semantics)
__device__ __forceinline__ unsigned pack2t(float a, float b) {
    unsigned ba = __builtin_bit_cast(unsigned, a);
    unsigned bb = __builtin_bit_cast(unsigned, b);
    return (ba >> 16) | (bb & 0xffff0000u);
}
// K=16 bf16 MFMA: A[m=lm][k=quad*4+r], B[k=quad*4+r][n=lm], D[m=quad*4+r][n=lm]
__device__ __forceinline__ f32x4 mfma16(short4v a, short4v b, f32x4 c) {
#if __has_builtin(__builtin_amdgcn_mfma_f32_16x16x16bf16_1k)
    return __builtin_amdgcn_mfma_f32_16x16x16bf16_1k(a, b, c, 0, 0, 0);
#else
    asm("v_mfma_f32_16x16x16_bf16 %0, %1, %2, %0" : "+v"(c) : "v"(a), "v"(b));
    return c;
#endif
}
// async 16B/lane global->LDS; lp must be wave-uniform base, lanes scatter +lane*16
__device__ __forceinline__ void glds16(const void* gp, void* lp) {
    __builtin_amdgcn_global_load_lds((const AS1 unsigned*)(uintptr_t)gp,
                                     (AS3 unsigned*)(unsigned)(uintptr_t)lp, 16, 0, 0);
}

// ------- fused prep: xin fp32->bf16 flat convert + both weight transposes -------
// Three independent passes merged into ONE dispatch (block-uniform branch per
// block range; per-block code identical to the old xbf_k / t32cvt_k -> numerics
// bit-identical). Removes 2 launch gaps and overlaps the three streams.
__global__ __launch_bounds__(256) void prep_k(const float* __restrict__ x,
                                              unsigned short* __restrict__ xb,
                                              const float* __restrict__ wqkv,
                                              unsigned short* __restrict__ wqkvT,
                                              const float* __restrict__ wo,
                                              unsigned short* __restrict__ woT) {
    __shared__ float tile[32][36];
    int bid = blockIdx.x;
    int t = threadIdx.x;
    if (bid < 8192) {                      // xbf: 8192 blocks
        int i = (bid * 256 + t) * 4;
        float4 v = *(const float4*)(x + i);
        uint2 u;
        u.x = pack2(v.x, v.y);
        u.y = pack2(v.z, v.w);
        *(uint2*)(xb + i) = u;
        return;                            // block-uniform: no thread reaches the barrier
    }
    const float* src; unsigned short* dst; int R, C, bx, by;
    if (bid < 8192 + 3072) {               // wqkv transpose: 96 x 32 blocks
        int b2 = bid - 8192;
        bx = b2 % 96; by = b2 / 96; src = wqkv; dst = wqkvT; R = 1024; C = 3072;
    } else {                               // wo transpose: 32 x 32 blocks
        int b3 = bid - 11264;
        bx = b3 & 31; by = b3 >> 5; src = wo; dst = woT; R = 1024; C = 1024;
    }
    int r = t >> 3, c0 = (t & 7) * 4;
    *(float4*)&tile[r][c0] = *(const float4*)(src + (size_t)(by * 32 + r) * C + bx * 32 + c0);
    __syncthreads();
    uint2 u;
    u.x = pack2(tile[c0 + 0][r], tile[c0 + 1][r]);
    u.y = pack2(tile[c0 + 2][r], tile[c0 + 3][r]);
    *(uint2*)(dst + (size_t)(bx * 32 + r) * R + by * 32 + c0) = u;
}

// ---- GEMM (2-phase 128², proven): C[M,N] = A[M,K] bf16 * Bt[N,K]^T bf16 ----
// T3 minimum 2-phase: single barrier per K-step, double-buffered LDS; the glds16
// loads for tile t+1 are issued before compute(t) and drained by the NEXT
// iteration's __syncthreads (vmcnt(0) before s_barrier) -> load latency hides
// under the MFMA phase. T1 XCD swizzle (grids % 8 == 0 here). T5 setprio.
template <bool CF32>
__global__ __launch_bounds__(256) void gemm_k(const unsigned short* __restrict__ A,
                                              const unsigned short* __restrict__ Bt,
                                              void* __restrict__ Cv,
                                              int M, int N, int K) {
    __shared__ unsigned short sA[2][128 * 32];   // [row][32] unpadded (glds16 linear)
    __shared__ unsigned short sB[2][128 * 32];
    int t = threadIdx.x;
    int wid = t >> 6, lane = t & 63;
    int wm = (wid >> 1) * 64, wn = (wid & 1) * 64;
    int lm = lane & 15, lq = lane >> 4;
    int nwg = gridDim.x * gridDim.y;
    int orig = blockIdx.y * gridDim.x + blockIdx.x;
    int swz = (orig & 7) * (nwg >> 3) + (orig >> 3);
    int bxi = swz % gridDim.x, byi = swz / gridDim.x;
    size_t m0 = (size_t)byi * 128, n0 = (size_t)bxi * 128;
    int srow = t >> 2, scol = (t & 3) * 8;
    const unsigned short* ga0 = A + (m0 + srow) * K + scol;
    const unsigned short* ga1 = A + (m0 + 64 + srow) * K + scol;
    const unsigned short* gb0 = Bt + (n0 + srow) * K + scol;
    const unsigned short* gb1 = Bt + (n0 + 64 + srow) * K + scol;
    int l0 = wid * 512, l1 = 2048 + wid * 512;

    // prologue: stage tile 0 into buf 0
    glds16(ga0, &sA[0][l0]);
    glds16(ga1, &sA[0][l1]);
    glds16(gb0, &sB[0][l0]);
    glds16(gb1, &sB[0][l1]);

    f32x4 acc[4][4] = {};
    int cur = 0;
    for (int k0 = 0; k0 < K; k0 += 32) {
        __syncthreads();   // per-wave vmcnt(0)+lgkmcnt(0) then s_barrier: buf[cur] ready,
                           // and all waves' reads of buf[cur^1] retired -> safe to restage.
        if (k0 + 32 < K) {
            glds16(ga0 + k0 + 32, &sA[cur ^ 1][l0]);
            glds16(ga1 + k0 + 32, &sA[cur ^ 1][l1]);
            glds16(gb0 + k0 + 32, &sB[cur ^ 1][l0]);
            glds16(gb1 + k0 + 32, &sB[cur ^ 1][l1]);
        }
        short8 af[4], bfr[4];
        #pragma unroll
        for (int i = 0; i < 4; ++i) af[i] = *(const short8*)&sA[cur][(wm + i * 16 + lm) * 32 + lq * 8];
        #pragma unroll
        for (int j = 0; j < 4; ++j) bfr[j] = *(const short8*)&sB[cur][(wn + j * 16 + lm) * 32 + lq * 8];
        __builtin_amdgcn_s_setprio(1);
        #pragma unroll
        for (int i = 0; i < 4; ++i)
            #pragma unroll
            for (int j = 0; j < 4; ++j)
                acc[i][j] = __builtin_amdgcn_mfma_f32_16x16x32_bf16(af[i], bfr[j], acc[i][j], 0, 0, 0);
        __builtin_amdgcn_s_setprio(0);
        cur ^= 1;
    }
    #pragma unroll
    for (int i = 0; i < 4; ++i)
        #pragma unroll
        for (int j = 0; j < 4; ++j)
            #pragma unroll
            for (int r = 0; r < 4; ++r) {
                size_t row = m0 + wm + i * 16 + lq * 4 + r;
                size_t col = n0 + wn + j * 16 + lm;
                if (CF32) ((float*)Cv)[row * N + col] = acc[i][j][r];
                else ((unsigned short*)Cv)[row * N + col] = f2bfbits(acc[i][j][r]);
            }
}

// ------- V transpose: per (b,h): V[2048 k][64 d] -> Vt[64 d][2048 k], bf16 -------
__global__ __launch_bounds__(256) void vt_k(const unsigned short* __restrict__ qkv,
                                            unsigned short* __restrict__ vt) {
    __shared__ unsigned short tile[64 * 72];
    int kt = blockIdx.x, bh = blockIdx.y;
    int b = bh >> 4, h = bh & 15;
    const unsigned short* Vp = qkv + (size_t)b * 6291456 + 4194304 + (size_t)h * 131072;
    int t = threadIdx.x;
    int row = t >> 2, cc = (t & 3) * 16;
    const unsigned short* src = Vp + (size_t)(kt * 64 + row) * 64 + cc;
    *(uint4*)&tile[row * 72 + cc] = *(const uint4*)src;
    *(uint4*)&tile[row * 72 + cc + 8] = *(const uint4*)(src + 8);
    __syncthreads();
    unsigned v[8];
    #pragma unroll
    for (int j = 0; j < 8; ++j) {
        unsigned short a = tile[(cc + 2 * j) * 72 + row];
        unsigned short bsh = tile[(cc + 2 * j + 1) * 72 + row];
        v[j] = (unsigned)a | ((unsigned)bsh << 16);
    }
    unsigned short* dst = vt + ((size_t)bh * 64 + row) * 2048 + kt * 64 + cc;
    *(uint4*)dst = make_uint4(v[0], v[1], v[2], v[3]);
    *(uint4*)(dst + 8) = make_uint4(v[4], v[5], v[6], v[7]);
}

// ------- MFMA flash attention: block = (b,h, 128-q); 4 waves x 32 q -------
// (round-4 best-measured variant, 94.3 us) Reg-resident P (swapped QK^T -> x16 PV).
// Double-buffered K/V LDS in T14 order: prefetch EARLY (after barrier), ds_write
// LATE (after compute) into the other buffer -> 1 barrier/kt, no VGPR WAR window.
__global__ __launch_bounds__(256, 4) void attn_mfma(const unsigned short* __restrict__ qkv,
                                                    const unsigned short* __restrict__ vt,
                                                    unsigned short* __restrict__ aout) {
    __shared__ unsigned short Ks[2][64 * 72];  // [kk 64][d 64] pad 72
    __shared__ unsigned short Vs[2][64 * 72];  // [d 64][kk 64] pad 72
    int bid0 = blockIdx.x;
    int bid = (bid0 & 7) * 128 + (bid0 >> 3);  // XCD swizzle, nwg=1024 (%8==0 -> bijective)
    int qt = bid & 15, h = (bid >> 4) & 15, b = bid >> 8;
    int t = threadIdx.x;
    int wave = t >> 6, lane = t & 63, lm = lane & 15, quad = lane >> 4;
    const unsigned short* Qb = qkv + (size_t)b * 6291456 + (size_t)h * 131072;
    const unsigned short* Kb = Qb + 2097152;
    const unsigned short* Vtb = vt + (size_t)(b * 16 + h) * 131072;  // [64][2048]
    int q0 = qt * 128 + wave * 32;

    // persistent Q fragments, pre-scaled by 0.125 * log2(e) (folds softmax scale + exp2 base)
    const float qs = 0.125f * LOG2E;
    short8 qf[2][2];
    #pragma unroll
    for (int i = 0; i < 2; ++i)
        #pragma unroll
        for (int c = 0; c < 2; ++c) {
            uint4 u = *(const uint4*)(Qb + (size_t)(q0 + i * 16 + lm) * 64 + c * 32 + quad * 8);
            float4 f0, f1; unpack8(u, f0, f1);
            uint4 v;
            v.x = pack2(f0.x * qs, f0.y * qs);
            v.y = pack2(f0.z * qs, f0.w * qs);
            v.z = pack2(f1.x * qs, f1.y * qs);
            v.w = pack2(f1.z * qs, f1.w * qs);
            qf[i][c] = *(short8*)&v;
        }

    short4v ones4;
    #pragma unroll
    for (int z = 0; z < 4; ++z) ones4[z] = (short)0x3F80;  // bf16 1.0

    f32x4 o[2][4] = {};
    f32x4 l_acc[2] = {};

    int srow = t >> 2, scol = (t & 3) * 16;

    // prologue: load tile 0 and stage it into buf0
    uint4 k0r, k1r, v0r, v1r;
    {
        const unsigned short* kp = Kb + (size_t)srow * 64 + scol;
        k0r = *(const uint4*)kp;
        k1r = *(const uint4*)(kp + 8);
        const unsigned short* vp = Vtb + (size_t)srow * 2048 + scol;
        v0r = *(const uint4*)vp;
        v1r = *(const uint4*)(vp + 8);
        *(uint4*)&Ks[0][srow * 72 + scol] = k0r;
        *(uint4*)&Ks[0][srow * 72 + scol + 8] = k1r;
        *(uint4*)&Vs[0][srow * 72 + scol] = v0r;
        *(uint4*)&Vs[0][srow * 72 + scol + 8] = v1r;
    }

    #pragma unroll 1
    for (int kt = 0; kt < 32; ++kt) {
        __syncthreads();   // buf[kt&1] (staged at end of prev iter / prologue) visible

        // issue next tile's global loads now; they land during this tile's compute
        if (kt < 31) {
            const unsigned short* kp = Kb + (size_t)((kt + 1) * 64 + srow) * 64 + scol;
            k0r = *(const uint4*)kp;
            k1r = *(const uint4*)(kp + 8);
            const unsigned short* vp = Vtb + (size_t)srow * 2048 + (kt + 1) * 64 + scol;
            v0r = *(const uint4*)vp;
            v1r = *(const uint4*)(vp + 8);
        }

        const unsigned short* ks = Ks[kt & 1];
        const unsigned short* vs = Vs[kt & 1];
        __builtin_amdgcn_s_setprio(1);

        // S^T = K Q^T per 16x16 tile: mfma(kf, qf) -> D[row=k-local][col=q-local].
        // Lane (lm,quad) holds P[q=i*16+lm][k=j*16+quad*4+0..3] == A-fragment of the
        // K=16 MFMA -> exp2+pack to short4 in registers, feed PV directly.
        short4v pf[2][4];
        #pragma unroll
        for (int j = 0; j < 4; ++j) {
            short8 kf0 = *(const short8*)&ks[(j * 16 + lm) * 72 + quad * 8];
            short8 kf1 = *(const short8*)&ks[(j * 16 + lm) * 72 + 32 + quad * 8];
            #pragma unroll
            for (int i = 0; i < 2; ++i) {
                f32x4 sf = {0.f, 0.f, 0.f, 0.f};
                sf = __builtin_amdgcn_mfma_f32_16x16x32_bf16(kf0, qf[i][0], sf, 0, 0, 0);
                sf = __builtin_amdgcn_mfma_f32_16x16x32_bf16(kf1, qf[i][1], sf, 0, 0, 0);
                uint2 u;
                u.x = pack2t(fexp2(sf[0]), fexp2(sf[1]));
                u.y = pack2t(fexp2(sf[2]), fexp2(sf[3]));
                pf[i][j] = *(short4v*)&u;
            }
        }

        // O += P V (K=16 MFMA, P from regs; V fragment = ds_read_b64 from Vt layout)
        #pragma unroll
        for (int jd = 0; jd < 4; ++jd)
            #pragma unroll
            for (int j = 0; j < 4; ++j) {
                short4v vf = *(const short4v*)&vs[(jd * 16 + lm) * 72 + j * 16 + quad * 4];
                o[0][jd] = mfma16(pf[0][j], vf, o[0][jd]);
                o[1][jd] = mfma16(pf[1][j], vf, o[1][jd]);
            }
        // l += P * ones (row-sums on MFMA pipe, same D layout as o)
        #pragma unroll
        for (int j = 0; j < 4; ++j) {
            l_acc[0] = mfma16(pf[0][j], ones4, l_acc[0]);
            l_acc[1] = mfma16(pf[1][j], ones4, l_acc[1]);
        }
        __builtin_amdgcn_s_setprio(0);

        // write-late: stage tile kt+1 into the other buffer. Safe with 1 barrier/kt:
        // any wave's reads of buf[(kt+1)&1] (its compute at kt-1) completed before it
        // arrived at barrier(kt), which this wave has passed.
        if (kt < 31) {
            unsigned short* kd = Ks[(kt + 1) & 1];
            unsigned short* vd = Vs[(kt + 1) & 1];
            *(uint4*)&kd[srow * 72 + scol] = k0r;
            *(uint4*)&kd[srow * 72 + scol + 8] = k1r;
            *(uint4*)&vd[srow * 72 + scol] = v0r;
            *(uint4*)&vd[srow * 72 + scol + 8] = v1r;
        }
    }
    // epilogue: aout[b*2048 + q][h*64 + d] bf16
    #pragma unroll
    for (int i = 0; i < 2; ++i)
        #pragma unroll
        for (int r = 0; r < 4; ++r) {
            float inv = 1.f / l_acc[i][r];
            int q = q0 + i * 16 + quad * 4 + r;
            size_t rowbase = ((size_t)b * 2048 + q) * 1024 + h * 64;
            #pragma unroll
            for (int jd = 0; jd < 4; ++jd)
                aout[rowbase + jd * 16 + lm] = f2bfbits(o[i][jd][r] * inv);
        }
}

extern "C" void kernel_launch(void* const* d_in, const int* in_sizes, int n_in,
                              void* d_out, int out_size, void* d_ws, size_t ws_size,
                              hipStream_t stream) {
    const float* xin  = (const float*)d_in[0];   // [8192,1024] fp32
    const float* wqkv = (const float*)d_in[1];   // [1024,3072] fp32
    const float* wo   = (const float*)d_in[2];   // [1024,1024] fp32
    float* out = (float*)d_out;                  // [8192,1024] fp32

    char* ws = (char*)d_ws;
    unsigned short* qkv   = (unsigned short*)(ws);                 // 50,331,648 B
    unsigned short* attn  = (unsigned short*)(ws + 50331648);      // 16,777,216 B
    unsigned short* wqkvT = (unsigned short*)(ws + 67108864);      //  6,291,456 B
    unsigned short* woT   = (unsigned short*)(ws + 73400320);      //  2,097,152 B
    unsigned short* vt    = (unsigned short*)(ws + 75497472);      // 16,777,216 B
    unsigned short* xb    = (unsigned short*)(ws + 92274688);      // 16,777,216 B

    dim3 blk(256);
    prep_k<<<dim3(12288), blk, 0, stream>>>(xin, xb, wqkv, wqkvT, wo, woT);
    gemm_k<false><<<dim3(3072 / 128, 8192 / 128), blk, 0, stream>>>(xb, wqkvT, qkv, 8192, 3072, 1024);
    vt_k<<<dim3(32, 64), blk, 0, stream>>>(qkv, vt);
    attn_mfma<<<dim3(1024), blk, 0, stream>>>(qkv, vt, attn);
    gemm_k<true><<<dim3(1024 / 128, 8192 / 128), blk, 0, stream>>>(attn, woT, out, 8192, 1024, 1024);
}